// Round 7
// baseline (141.863 us; speedup 1.0000x reference)
//
#include <hip/hip_runtime.h>

// Head: k = x@Wk^T; q = k (source bug); wei = softmax(causal(q k^T / 8)); v = x@Wv^T; out = wei@v
// B=8, T=2048, C=1024, H=64. fp32 in/out, bf16 MFMA internally.
//
// R6 -> R7: latency exposure. proj: grid 1024 (16x128 tiles, 39 KB LDS -> 4 blocks/CU
// = 16 waves/CU), loads issued at top of iter (cover = MFMA + LDS-store phase).
// attn: 128-row q-tiles, each wave owns TWO 16-row strips (2x ILP, half the iters/
// staging/barriers per flop), grid 512 (4-way KV split), strip0's fully-masked tail
// tile skipped wave-uniformly.

typedef __bf16 bf16;
typedef __bf16 bf16x4 __attribute__((ext_vector_type(4)));
typedef __bf16 bf16x8 __attribute__((ext_vector_type(8)));
typedef float  floatx4 __attribute__((ext_vector_type(4)));

#define T_LEN 2048
#define HEAD  64
#define CEMB  1024

static __device__ __forceinline__ bf16x8 cvt2(float4 a, float4 b) {
    bf16x8 r;
    r[0] = (bf16)a.x; r[1] = (bf16)a.y; r[2] = (bf16)a.z; r[3] = (bf16)a.w;
    r[4] = (bf16)b.x; r[5] = (bf16)b.y; r[6] = (bf16)b.z; r[7] = (bf16)b.w;
    return r;
}
static __device__ __forceinline__ bf16x4 cvt1(float4 a) {
    bf16x4 r;
    r[0] = (bf16)a.x; r[1] = (bf16)a.y; r[2] = (bf16)a.z; r[3] = (bf16)a.w;
    return r;
}

// ---------------- Kernel 0: W fp32 -> bf16, [Wk;Wv] concat as Wb[128][1024]
__global__ __launch_bounds__(256) void wconv_kernel(const float* __restrict__ Wk,
                                                    const float* __restrict__ Wv,
                                                    bf16* __restrict__ Wb) {
    int i = (blockIdx.x * 256 + threadIdx.x) * 4;   // grid 128 covers 131072
    const float* src = (i < 64 * 1024) ? (Wk + i) : (Wv + (i - 64 * 1024));
    float4 f = *(const float4*)src;
    *(bf16x4*)&Wb[i] = cvt1(f);
}

// ---------------- Kernel 1: projection GEMM. grid 1024, tile 16 rows x 128 cols, BK=64.
// 4 blocks/CU. Double-buffered LDS + depth-2 reg prefetch, loads at top of iteration.
__global__ __launch_bounds__(256) void proj_kernel(const float* __restrict__ x,
                                                   const bf16* __restrict__ Wb,
                                                   bf16* __restrict__ Kbuf,
                                                   bf16* __restrict__ Vt) {
    __shared__ __align__(16) bf16 As[2][16][72];    // 4.6 KB
    __shared__ __align__(16) bf16 Bs[2][128][68];   // 34.8 KB -> total 39.4 KB

    const int tid  = threadIdx.x;
    const int wave = tid >> 6;
    const int lane = tid & 63;
    const int quad = lane >> 4;
    const int low  = lane & 15;

    const long row0 = (long)blockIdx.x * 16;

    const int a_row = tid >> 4;          // 0..15, 4 fp32/thread
    const int a_col = (tid & 15) * 4;
    const int b_row = tid >> 1;          // 0..127, 32 bf16/thread
    const int b_col = (tid & 1) * 32;

    const float* abase = x + (row0 + a_row) * CEMB + a_col;
    const bf16*  bbase = Wb + b_row * CEMB + b_col;

    const int nt0 = wave * 2;            // wave covers cols [wave*32, wave*32+32)

    floatx4 acc[2];
    acc[0] = (floatx4){0.f, 0.f, 0.f, 0.f};
    acc[1] = (floatx4){0.f, 0.f, 0.f, 0.f};

    float4 apf[2];
    bf16x8 bpf[2][4];

    // prologue: step0 -> LDS0; step1 -> regs set1
    apf[0] = *(const float4*)abase;
#pragma unroll
    for (int i = 0; i < 4; ++i) bpf[0][i] = *(const bf16x8*)(bbase + 8 * i);
    *(bf16x4*)&As[0][a_row][a_col] = cvt1(apf[0]);
#pragma unroll
    for (int i = 0; i < 4; ++i) *(bf16x8*)&Bs[0][b_row][b_col + 8 * i] = bpf[0][i];
    apf[1] = *(const float4*)(abase + 64);
#pragma unroll
    for (int i = 0; i < 4; ++i) bpf[1][i] = *(const bf16x8*)(bbase + 64 + 8 * i);
    __syncthreads();

    int buf = 0;
    for (int s = 0; s < 16; ++s) {
        // loads for s+2 first: max distance to the barrier's vmcnt drain
        if (s < 14) {
            const int q  = s & 1;
            const int k0 = (s + 2) * 64;
            apf[q] = *(const float4*)(abase + k0);
#pragma unroll
            for (int i = 0; i < 4; ++i) bpf[q][i] = *(const bf16x8*)(bbase + k0 + 8 * i);
        }
        // compute step s from LDS[buf]
#pragma unroll
        for (int ks = 0; ks < 2; ++ks) {
            bf16x8 afrag = *(const bf16x8*)&As[buf][low][ks * 32 + quad * 8];
#pragma unroll
            for (int i = 0; i < 2; ++i) {
                bf16x8 bfrag = *(const bf16x8*)&Bs[buf][(nt0 + i) * 16 + low][ks * 32 + quad * 8];
                acc[i] = __builtin_amdgcn_mfma_f32_16x16x32_bf16(afrag, bfrag, acc[i], 0, 0, 0);
            }
        }
        // store step s+1 (regs landed during iter s-1) to alternate buffer
        if (s < 15) {
            const int q  = (s + 1) & 1;
            const int nb = buf ^ 1;
            *(bf16x4*)&As[nb][a_row][a_col] = cvt1(apf[q]);
#pragma unroll
            for (int i = 0; i < 4; ++i) *(bf16x8*)&Bs[nb][b_row][b_col + 8 * i] = bpf[q][i];
            __syncthreads();
            buf = nb;
        }
    }

    // epilogue via LDS transpose (alias Bs): coalesced stores.
    __syncthreads();
    bf16* Ek = (bf16*)&Bs[0][0][0];   // [16][72]: Ek[t][h]
    bf16* Ev = (bf16*)&Bs[1][0][0];   // [64][20]: Ev[h][t]
    if (wave < 2) {
#pragma unroll
        for (int i = 0; i < 2; ++i)
#pragma unroll
            for (int r = 0; r < 4; ++r)
                Ek[(quad * 4 + r) * 72 + wave * 32 + i * 16 + low] = (bf16)acc[i][r];
    } else {
#pragma unroll
        for (int i = 0; i < 2; ++i)
#pragma unroll
            for (int r = 0; r < 4; ++r)
                Ev[((wave - 2) * 32 + i * 16 + low) * 20 + quad * 4 + r] = (bf16)acc[i][r];
    }
    __syncthreads();

    const long bidx  = row0 >> 11;
    const int  tloc0 = (int)(row0 & 2047);
    {   // K: thread t=tid>>4 (0..15), h0=(tid&15)*4 -> 8B contiguous
        const int t  = tid >> 4;
        const int h0 = (tid & 15) * 4;
        *(bf16x4*)&Kbuf[(bidx * T_LEN + tloc0 + t) * HEAD + h0] = *(const bf16x4*)&Ek[t * 72 + h0];
    }
    {   // V: thread h=tid>>2 (0..63), t0=(tid&3)*4
        const int h  = tid >> 2;
        const int t0 = (tid & 3) * 4;
        *(bf16x4*)&Vt[(bidx * HEAD + h) * T_LEN + tloc0 + t0] = *(const bf16x4*)&Ev[h * 20 + t0];
    }
}

// ---------------- Kernel 2: attention partial. q=k, causal, scale 1/8, fixed-max softmax.
// 128-row q-tiles; wave owns strips t0=qt*128+wave*16 and t1=+64.
// blockIdx.x = ((b*16 + qt)*4 + c); chunk c: kv tiles j in {c, c+4, ...} <= 2qt+1.
__global__ __launch_bounds__(256) void attn_kernel(const bf16* __restrict__ Kbuf,
                                                   const bf16* __restrict__ Vt,
                                                   bf16* __restrict__ Opart,
                                                   float* __restrict__ lpart) {
    __shared__ __align__(16) bf16 Ks[2][64][72];
    __shared__ __align__(16) bf16 Vs[2][64][72];       // [h][kv]
    __shared__ __align__(16) bf16 Ps[4][2][16][72];    // per-wave, per-strip

    const int tid  = threadIdx.x;
    const int wave = tid >> 6;
    const int lane = tid & 63;
    const int quad = lane >> 4;
    const int low  = lane & 15;

    const int c  = blockIdx.x & 3;
    const int qt = (blockIdx.x >> 2) & 15;
    const int b  = blockIdx.x >> 6;

    const bf16* kbase = Kbuf + (long)b * T_LEN * HEAD;
    const bf16* vbase = Vt + (long)b * HEAD * T_LEN;

    // Q fragments for both strips (A-layout) direct from global
    bf16x8 qf[2][2];
#pragma unroll
    for (int t = 0; t < 2; ++t) {
        const bf16* qrow = kbase + (qt * 128 + t * 64 + wave * 16 + low) * HEAD + quad * 8;
        qf[t][0] = *(const bf16x8*)(qrow);
        qf[t][1] = *(const bf16x8*)(qrow + 32);
    }

    bf16x8 ones;
#pragma unroll
    for (int i = 0; i < 8; ++i) ones[i] = (bf16)1.0f;

    floatx4 o[2][4], ol[2];
#pragma unroll
    for (int t = 0; t < 2; ++t) {
#pragma unroll
        for (int nt = 0; nt < 4; ++nt) o[t][nt] = (floatx4){0.f, 0.f, 0.f, 0.f};
        ol[t] = (floatx4){0.f, 0.f, 0.f, 0.f};
    }

    const int jmax = 2 * qt + 1;
    const int jd0  = 2 * qt;

    const int s_row = tid >> 2;          // 0..63
    const int s_col = (tid & 3) * 16;
    const bf16* ksrc = kbase + s_row * HEAD + s_col;
    const bf16* vsrc = vbase + (long)s_row * T_LEN + s_col;

    if (c <= jmax) {
        float4 kpf0 = *(const float4*)(ksrc + c * 4096);
        float4 kpf1 = *(const float4*)(ksrc + c * 4096 + 8);
        float4 vpf0 = *(const float4*)(vsrc + c * 64);
        float4 vpf1 = *(const float4*)(vsrc + c * 64 + 8);
        *(float4*)&Ks[0][s_row][s_col]     = kpf0;
        *(float4*)&Ks[0][s_row][s_col + 8] = kpf1;
        *(float4*)&Vs[0][s_row][s_col]     = vpf0;
        *(float4*)&Vs[0][s_row][s_col + 8] = vpf1;
        __syncthreads();

        int buf = 0;
        for (int j = c; j <= jmax; j += 4) {
            const bool more = (j + 4 <= jmax);
            if (more) {   // prefetch next tile first (max cover before barrier drain)
                kpf0 = *(const float4*)(ksrc + (j + 4) * 4096);
                kpf1 = *(const float4*)(ksrc + (j + 4) * 4096 + 8);
                vpf0 = *(const float4*)(vsrc + (j + 4) * 64);
                vpf1 = *(const float4*)(vsrc + (j + 4) * 64 + 8);
            }

#pragma unroll
            for (int t = 0; t < 2; ++t) {
                if (t == 0 && j > jd0) continue;   // strip0 fully masked at j = jd0+1 (uniform)
                // S = Q_t K^T
                floatx4 s_[4];
#pragma unroll
                for (int nt = 0; nt < 4; ++nt) {
                    bf16x8 kf0 = *(const bf16x8*)&Ks[buf][nt * 16 + low][quad * 8];
                    bf16x8 kf1 = *(const bf16x8*)&Ks[buf][nt * 16 + low][32 + quad * 8];
                    floatx4 z = (floatx4){0.f, 0.f, 0.f, 0.f};
                    z = __builtin_amdgcn_mfma_f32_16x16x32_bf16(qf[t][0], kf0, z, 0, 0, 0);
                    z = __builtin_amdgcn_mfma_f32_16x16x32_bf16(qf[t][1], kf1, z, 0, 0, 0);
                    s_[nt] = z;
                }
                const bool diag = (j == jd0 + t);
#pragma unroll
                for (int nt = 0; nt < 4; ++nt) {
#pragma unroll
                    for (int r = 0; r < 4; ++r) {
                        float p = __builtin_amdgcn_exp2f(s_[nt][r] * 0.180336880f);
                        if (diag && (nt * 16 + low) > (wave * 16 + quad * 4 + r)) p = 0.f;
                        Ps[wave][t][quad * 4 + r][nt * 16 + low] = (bf16)p;
                    }
                }
                bf16x8 pf0 = *(const bf16x8*)&Ps[wave][t][low][quad * 8];
                bf16x8 pf1 = *(const bf16x8*)&Ps[wave][t][low][32 + quad * 8];
#pragma unroll
                for (int nt = 0; nt < 4; ++nt) {
                    bf16x8 vf0 = *(const bf16x8*)&Vs[buf][nt * 16 + low][quad * 8];
                    bf16x8 vf1 = *(const bf16x8*)&Vs[buf][nt * 16 + low][32 + quad * 8];
                    o[t][nt] = __builtin_amdgcn_mfma_f32_16x16x32_bf16(pf0, vf0, o[t][nt], 0, 0, 0);
                    o[t][nt] = __builtin_amdgcn_mfma_f32_16x16x32_bf16(pf1, vf1, o[t][nt], 0, 0, 0);
                }
                ol[t] = __builtin_amdgcn_mfma_f32_16x16x32_bf16(pf0, ones, ol[t], 0, 0, 0);
                ol[t] = __builtin_amdgcn_mfma_f32_16x16x32_bf16(pf1, ones, ol[t], 0, 0, 0);
            }

            if (more) {
                const int nb = buf ^ 1;
                *(float4*)&Ks[nb][s_row][s_col]     = kpf0;
                *(float4*)&Ks[nb][s_row][s_col + 8] = kpf1;
                *(float4*)&Vs[nb][s_row][s_col]     = vpf0;
                *(float4*)&Vs[nb][s_row][s_col + 8] = vpf1;
                __syncthreads();
                buf = nb;
            }
        }
    }

    // epilogue: transpose both strips through LDS (alias Ks = 128 rows x 72), coalesced store
    __syncthreads();
    bf16* Eo = (bf16*)&Ks[0][0][0];
#pragma unroll
    for (int t = 0; t < 2; ++t)
#pragma unroll
        for (int nt = 0; nt < 4; ++nt)
#pragma unroll
            for (int r = 0; r < 4; ++r)
                Eo[(t * 64 + wave * 16 + quad * 4 + r) * 72 + nt * 16 + low] = (bf16)o[t][nt][r];
    __syncthreads();
    {
        const int row  = tid >> 1;           // 0..127
        const int col0 = (tid & 1) * 32;
        bf16* ob = Opart + (long)blockIdx.x * 8192 + row * 64 + col0;
#pragma unroll
        for (int i = 0; i < 4; ++i)
            *(bf16x8*)(ob + 8 * i) = *(const bf16x8*)&Eo[row * 72 + col0 + 8 * i];
    }
    if (low == 0) {
#pragma unroll
        for (int t = 0; t < 2; ++t)
#pragma unroll
            for (int r = 0; r < 4; ++r)
                lpart[(long)blockIdx.x * 128 + t * 64 + wave * 16 + quad * 4 + r] = ol[t][r];
    }
}

// ---------------- Kernel 3: combine 4 chunks. grid 256 (one 64-row tile each).
__global__ __launch_bounds__(256) void attn_combine(const bf16* __restrict__ Opart,
                                                    const float* __restrict__ lpart,
                                                    float* __restrict__ out) {
    const int g    = blockIdx.x;         // b*32 + t64
    const int b    = g >> 5;
    const int t64  = g & 31;
    const int qt   = t64 >> 1;
    const int half = t64 & 1;
    const int tid  = threadIdx.x;
    const int row  = tid >> 2;           // 0..63
    const int col0 = (tid & 3) * 16;

    const long blk0 = ((long)(b * 16 + qt)) * 4;
    const int  lrow = half * 64 + row;

    float l = 0.f;
#pragma unroll
    for (int ch = 0; ch < 4; ++ch) l += lpart[(blk0 + ch) * 128 + lrow];
    float rl = 1.0f / l;

    float s[16];
#pragma unroll
    for (int i = 0; i < 16; ++i) s[i] = 0.f;
#pragma unroll
    for (int ch = 0; ch < 4; ++ch) {
        const bf16* ob = Opart + (blk0 + ch) * 8192 + lrow * 64 + col0;
        bf16x8 u0 = *(const bf16x8*)(ob);
        bf16x8 u1 = *(const bf16x8*)(ob + 8);
#pragma unroll
        for (int i = 0; i < 8; ++i) { s[i] += (float)u0[i]; s[8 + i] += (float)u1[i]; }
    }
    float4* op = (float4*)(out + ((long)b * T_LEN + t64 * 64 + row) * HEAD + col0);
#pragma unroll
    for (int v = 0; v < 4; ++v) {
        float4 w;
        w.x = s[v * 4 + 0] * rl; w.y = s[v * 4 + 1] * rl;
        w.z = s[v * 4 + 2] * rl; w.w = s[v * 4 + 3] * rl;
        op[v] = w;
    }
}

extern "C" void kernel_launch(void* const* d_in, const int* in_sizes, int n_in,
                              void* d_out, int out_size, void* d_ws, size_t ws_size,
                              hipStream_t stream) {
    const float* x  = (const float*)d_in[0];
    const float* Wk = (const float*)d_in[1];
    const float* Wv = (const float*)d_in[2];
    float* out = (float*)d_out;

    char* ws = (char*)d_ws;
    bf16*  Wb    = (bf16*)ws;                           // 256 KB
    bf16*  Kbuf  = (bf16*)(ws + (1 << 20));             // 2 MB
    bf16*  Vt    = (bf16*)(ws + (3 << 20));             // 2 MB
    bf16*  Opart = (bf16*)(ws + (5 << 20));             // 512*8192*2 = 8 MB
    float* lpart = (float*)(ws + (13 << 20));           // 512*128*4 = 256 KB

    wconv_kernel<<<128, 256, 0, stream>>>(Wk, Wv, Wb);
    proj_kernel<<<1024, 256, 0, stream>>>(x, Wb, Kbuf, Vt);
    attn_kernel<<<512, 256, 0, stream>>>(Kbuf, Vt, Opart, lpart);
    attn_combine<<<256, 256, 0, stream>>>(Opart, lpart, out);
}

// Round 8
// 131.295 us; speedup vs baseline: 1.0805x; 1.0805x over previous
//
#include <hip/hip_runtime.h>

// Head: k = x@Wk^T; q = k (source bug); wei = softmax(causal(q k^T / 8)); v = x@Wv^T; out = wei@v
// B=8, T=2048, C=1024, H=64. fp32 in/out, bf16 MFMA internally.
//
// R7 -> R8: revert to R6 shapes (proj 32x128 BK=64 grid 512; attn 64-row q-tiles,
// 4-way KV split grid 1024). Staging converted to __builtin_amdgcn_global_load_lds
// width-16 (async DMA, no VGPR round-trip, issued a full iteration before the
// barrier that drains it). Unpadded LDS tiles with XOR chunk swizzle
// (pos = chunk ^ (row & 7)) -> frag reads perfectly bank-balanced.

typedef __bf16 bf16;
typedef __bf16 bf16x4 __attribute__((ext_vector_type(4)));
typedef __bf16 bf16x8 __attribute__((ext_vector_type(8)));
typedef float  floatx4 __attribute__((ext_vector_type(4)));

#define T_LEN 2048
#define HEAD  64
#define CEMB  1024

static __device__ __forceinline__ void async16(const void* g, void* l) {
    __builtin_amdgcn_global_load_lds(
        (const __attribute__((address_space(1))) void*)g,
        (__attribute__((address_space(3))) void*)l, 16, 0, 0);
}

static __device__ __forceinline__ bf16x8 cvt2(float4 a, float4 b) {
    bf16x8 r;
    r[0] = (bf16)a.x; r[1] = (bf16)a.y; r[2] = (bf16)a.z; r[3] = (bf16)a.w;
    r[4] = (bf16)b.x; r[5] = (bf16)b.y; r[6] = (bf16)b.z; r[7] = (bf16)b.w;
    return r;
}
static __device__ __forceinline__ bf16x4 cvt1(float4 a) {
    bf16x4 r;
    r[0] = (bf16)a.x; r[1] = (bf16)a.y; r[2] = (bf16)a.z; r[3] = (bf16)a.w;
    return r;
}

// ---------------- Kernel 0: W fp32 -> bf16, [Wk;Wv] concat as Wb[128][1024]
__global__ __launch_bounds__(256) void wconv_kernel(const float* __restrict__ Wk,
                                                    const float* __restrict__ Wv,
                                                    bf16* __restrict__ Wb) {
    int i = (blockIdx.x * 256 + threadIdx.x) * 4;   // grid 128 covers 131072
    const float* src = (i < 64 * 1024) ? (Wk + i) : (Wv + (i - 64 * 1024));
    *(bf16x4*)&Wb[i] = cvt1(*(const float4*)src);
}

// ---------------- Kernel 1: projection GEMM. grid 512, tile 32 rows x 128 cols, BK=64.
// DMA double-buffered (global_load_lds w16), XOR-swizzled LDS, 1 barrier/K-step.
__global__ __launch_bounds__(256) void proj_kernel(const float* __restrict__ x,
                                                   const bf16* __restrict__ Wb,
                                                   bf16* __restrict__ Kbuf,
                                                   bf16* __restrict__ Vt) {
    __shared__ __align__(16) float As[2][32 * 64];   // fp32, 16-B chunk at (r, c^ (r&15))
    __shared__ __align__(16) bf16  Bs[2][128 * 64];  // bf16, 16-B chunk at (r, c^ (r&7))

    const int tid  = threadIdx.x;
    const int wave = tid >> 6;
    const int lane = tid & 63;
    const int quad = lane >> 4;
    const int low  = lane & 15;

    const long row0 = (long)blockIdx.x * 32;

    // DMA lane geometry
    const int ar_ = lane >> 4;                       // A sub-row within 4-row group
    const int ac_ = (lane & 15) ^ (wave * 4 + ar_);  // A swizzled global chunk
    const int br_ = lane >> 3;                       // B sub-row within 8-row group
    const int bc_ = (lane & 7) ^ br_;                // B swizzled global chunk

    const int strip = wave & 1;          // 16-row M strip
    const int nq    = (wave >> 1) * 4;   // waves 0,1 -> K cols; 2,3 -> V cols

    floatx4 acc[4];
#pragma unroll
    for (int i = 0; i < 4; ++i) acc[i] = (floatx4){0.f, 0.f, 0.f, 0.f};

    auto stage = [&](int s, int sb) {
        const int k0 = s * 64;
#pragma unroll
        for (int m = 0; m < 2; ++m) {    // A: 32x64 fp32, 2 DMA/wave
            const int r = (m * 4 + wave) * 4 + ar_;
            async16(x + (row0 + r) * CEMB + k0 + ac_ * 4, &As[sb][(m * 4 + wave) * 256]);
        }
#pragma unroll
        for (int m = 0; m < 4; ++m) {    // B: 128x64 bf16, 4 DMA/wave
            const int r = (m * 4 + wave) * 8 + br_;
            async16(Wb + r * CEMB + k0 + bc_ * 8, &Bs[sb][(m * 4 + wave) * 512]);
        }
    };

    stage(0, 0);
    stage(1, 1);
    __syncthreads();

    int buf = 0;
    for (int s = 0; s < 16; ++s) {
#pragma unroll
        for (int ks = 0; ks < 2; ++ks) {
            const int rr = strip * 16 + low;
            const int c0 = ks * 8 + quad * 2;
            float4 a0 = *(const float4*)&As[buf][rr * 64 + ((c0 ^ low) * 4)];
            float4 a1 = *(const float4*)&As[buf][rr * 64 + (((c0 + 1) ^ low) * 4)];
            bf16x8 afrag = cvt2(a0, a1);
            const int cq = ks * 4 + quad;
#pragma unroll
            for (int i = 0; i < 4; ++i) {
                const int r2 = (nq + i) * 16 + low;
                bf16x8 bfrag = *(const bf16x8*)&Bs[buf][r2 * 64 + ((cq ^ (low & 7)) * 8)];
                acc[i] = __builtin_amdgcn_mfma_f32_16x16x32_bf16(afrag, bfrag, acc[i], 0, 0, 0);
            }
        }
        if (s < 15) {
            __syncthreads();                 // drains (s+1) DMA; frees buf
            if (s < 14) stage(s + 2, buf);   // full iteration in flight before next drain
            buf ^= 1;
        }
    }

    // epilogue via LDS transpose (alias Bs): coalesced 16B stores
    __syncthreads();
    bf16* Ek = (bf16*)&Bs[0][0];   // [32][72]: Ek[t][h]
    bf16* Ev = (bf16*)&Bs[1][0];   // [64][36]: Ev[h][t]
    if (wave < 2) {
#pragma unroll
        for (int i = 0; i < 4; ++i)
#pragma unroll
            for (int r = 0; r < 4; ++r)
                Ek[(strip * 16 + quad * 4 + r) * 72 + i * 16 + low] = (bf16)acc[i][r];
    } else {
#pragma unroll
        for (int i = 0; i < 4; ++i)
#pragma unroll
            for (int r = 0; r < 4; ++r)
                Ev[(i * 16 + low) * 36 + strip * 16 + quad * 4 + r] = (bf16)acc[i][r];
    }
    __syncthreads();

    const long bidx  = row0 >> 11;
    const int  tloc0 = (int)(row0 & 2047);
    {   // K: thread t=tid>>3 (0..31), h0=(tid&7)*8 -> 16B contiguous
        const int t  = tid >> 3;
        const int h0 = (tid & 7) * 8;
        *(bf16x8*)&Kbuf[(bidx * T_LEN + tloc0 + t) * HEAD + h0] = *(const bf16x8*)&Ek[t * 72 + h0];
    }
    {   // V: thread h=tid>>2 (0..63), t0=(tid&3)*8
        const int h  = tid >> 2;
        const int t0 = (tid & 3) * 8;
        *(bf16x8*)&Vt[(bidx * HEAD + h) * T_LEN + tloc0 + t0] = *(const bf16x8*)&Ev[h * 36 + t0];
    }
}

// ---------------- Kernel 2: attention partial. q=k, causal, scale 1/8, fixed-max softmax.
// blockIdx.x = ((b*32 + qb)*4 + c); chunk c: kv tiles j in {c, c+4, ...} <= qb.
// K/V staged via global_load_lds into XOR-swizzled LDS, DMA double-buffered.
__global__ __launch_bounds__(256) void attn_kernel(const bf16* __restrict__ Kbuf,
                                                   const bf16* __restrict__ Vt,
                                                   bf16* __restrict__ Opart,
                                                   float* __restrict__ lpart) {
    __shared__ __align__(16) bf16 Ks[2][64 * 64];   // swizzled [kv][h]
    __shared__ __align__(16) bf16 Vs[2][64 * 64];   // swizzled [h][kv]
    __shared__ __align__(16) bf16 Ps[4][16][72];    // per-wave private

    const int tid  = threadIdx.x;
    const int wave = tid >> 6;
    const int lane = tid & 63;
    const int quad = lane >> 4;
    const int low  = lane & 15;

    const int c  = blockIdx.x & 3;
    const int qb = (blockIdx.x >> 2) & 31;
    const int b  = blockIdx.x >> 7;

    const bf16* kbase = Kbuf + (long)b * T_LEN * HEAD;
    const bf16* vbase = Vt + (long)b * HEAD * T_LEN;

    // Q fragments (A-layout) direct from global (once per block)
    const bf16* qrow = kbase + (qb * 64 + wave * 16 + low) * HEAD + quad * 8;
    const bf16x8 qf0 = *(const bf16x8*)(qrow);
    const bf16x8 qf1 = *(const bf16x8*)(qrow + 32);

    bf16x8 ones;
#pragma unroll
    for (int i = 0; i < 8; ++i) ones[i] = (bf16)1.0f;

    floatx4 o[4], ol;
#pragma unroll
    for (int nt = 0; nt < 4; ++nt) o[nt] = (floatx4){0.f, 0.f, 0.f, 0.f};
    ol = (floatx4){0.f, 0.f, 0.f, 0.f};

    const int br_ = lane >> 3;
    const int bc_ = (lane & 7) ^ br_;

    auto stage = [&](int j, int sb) {
#pragma unroll
        for (int m = 0; m < 2; ++m) {
            const int r = (m * 4 + wave) * 8 + br_;
            async16(kbase + (j * 64 + r) * HEAD + bc_ * 8, &Ks[sb][(m * 4 + wave) * 512]);
            async16(vbase + (long)r * T_LEN + j * 64 + bc_ * 8, &Vs[sb][(m * 4 + wave) * 512]);
        }
    };

    if (c <= qb) {
        stage(c, 0);
        if (c + 4 <= qb) stage(c + 4, 1);
        __syncthreads();

        int buf = 0;
        for (int j = c; j <= qb; j += 4) {
            // S = Q K^T ; per-wave S tile [16 x 64]
            floatx4 s_[4];
#pragma unroll
            for (int nt = 0; nt < 4; ++nt) {
                const int r2 = nt * 16 + low;
                bf16x8 kf0 = *(const bf16x8*)&Ks[buf][r2 * 64 + ((quad ^ (low & 7)) * 8)];
                bf16x8 kf1 = *(const bf16x8*)&Ks[buf][r2 * 64 + (((4 + quad) ^ (low & 7)) * 8)];
                floatx4 z = (floatx4){0.f, 0.f, 0.f, 0.f};
                z = __builtin_amdgcn_mfma_f32_16x16x32_bf16(qf0, kf0, z, 0, 0, 0);
                z = __builtin_amdgcn_mfma_f32_16x16x32_bf16(qf1, kf1, z, 0, 0, 0);
                s_[nt] = z;
            }

            // p = exp2(s * 0.125*log2e); causal mask on diagonal tile; P strip -> LDS
            const bool diag = (j == qb);
#pragma unroll
            for (int nt = 0; nt < 4; ++nt) {
#pragma unroll
                for (int r = 0; r < 4; ++r) {
                    float p = __builtin_amdgcn_exp2f(s_[nt][r] * 0.180336880f);
                    if (diag && (nt * 16 + low) > (wave * 16 + quad * 4 + r)) p = 0.f;
                    Ps[wave][quad * 4 + r][nt * 16 + low] = (bf16)p;
                }
            }

            // O += P V ; l += P . ones  (Ps wave-private: lgkmcnt ordering suffices)
            bf16x8 pf0 = *(const bf16x8*)&Ps[wave][low][quad * 8];
            bf16x8 pf1 = *(const bf16x8*)&Ps[wave][low][32 + quad * 8];
#pragma unroll
            for (int nt = 0; nt < 4; ++nt) {
                const int r2 = nt * 16 + low;
                bf16x8 vf0 = *(const bf16x8*)&Vs[buf][r2 * 64 + ((quad ^ (low & 7)) * 8)];
                bf16x8 vf1 = *(const bf16x8*)&Vs[buf][r2 * 64 + (((4 + quad) ^ (low & 7)) * 8)];
                o[nt] = __builtin_amdgcn_mfma_f32_16x16x32_bf16(pf0, vf0, o[nt], 0, 0, 0);
                o[nt] = __builtin_amdgcn_mfma_f32_16x16x32_bf16(pf1, vf1, o[nt], 0, 0, 0);
            }
            ol = __builtin_amdgcn_mfma_f32_16x16x32_bf16(pf0, ones, ol, 0, 0, 0);
            ol = __builtin_amdgcn_mfma_f32_16x16x32_bf16(pf1, ones, ol, 0, 0, 0);

            if (j + 4 <= qb) {
                __syncthreads();                      // drains (j+4) DMA; frees buf
                if (j + 8 <= qb) stage(j + 8, buf);   // full iteration in flight
                buf ^= 1;
            }
        }
    }

    // epilogue via LDS transpose (alias Ks): coalesced bf16 partial stores
    __syncthreads();
    bf16* Eo = (bf16*)&Ks[0][0];   // [64][72]
#pragma unroll
    for (int nt = 0; nt < 4; ++nt)
#pragma unroll
        for (int r = 0; r < 4; ++r)
            Eo[(wave * 16 + quad * 4 + r) * 72 + nt * 16 + low] = (bf16)o[nt][r];
    __syncthreads();
    {
        const int row  = tid >> 2;
        const int col0 = (tid & 3) * 16;
        bf16* ob = Opart + (long)blockIdx.x * 4096 + row * 64 + col0;
        *(bf16x8*)(ob)     = *(const bf16x8*)&Eo[row * 72 + col0];
        *(bf16x8*)(ob + 8) = *(const bf16x8*)&Eo[row * 72 + col0 + 8];
    }
    if (low == 0) {
#pragma unroll
        for (int r = 0; r < 4; ++r)
            lpart[(long)blockIdx.x * 64 + wave * 16 + quad * 4 + r] = ol[r];
    }
}

// ---------------- Kernel 3: combine 4 chunks. out = sum_c Opart / sum_c lpart.
__global__ __launch_bounds__(256) void attn_combine(const bf16* __restrict__ Opart,
                                                    const float* __restrict__ lpart,
                                                    float* __restrict__ out) {
    const int tile = blockIdx.x;         // 256 = b*32+qb
    const int tid  = threadIdx.x;
    const int row  = tid >> 2;           // 0..63
    const int col0 = (tid & 3) * 16;

    const bf16*  ob = Opart + (long)tile * 4 * 4096 + row * 64 + col0;
    const float* lb = lpart + (long)tile * 4 * 64 + row;

    float l = lb[0] + lb[64] + lb[128] + lb[192];
    float rl = 1.0f / l;

    float s[16];
#pragma unroll
    for (int i = 0; i < 16; ++i) s[i] = 0.f;
#pragma unroll
    for (int ch = 0; ch < 4; ++ch) {
        bf16x8 u0 = *(const bf16x8*)(ob + ch * 4096);
        bf16x8 u1 = *(const bf16x8*)(ob + ch * 4096 + 8);
#pragma unroll
        for (int i = 0; i < 8; ++i) { s[i] += (float)u0[i]; s[8 + i] += (float)u1[i]; }
    }
    float4* op = (float4*)(out + (long)tile * 4096 + row * 64 + col0);
#pragma unroll
    for (int v = 0; v < 4; ++v) {
        float4 w;
        w.x = s[v * 4 + 0] * rl; w.y = s[v * 4 + 1] * rl;
        w.z = s[v * 4 + 2] * rl; w.w = s[v * 4 + 3] * rl;
        op[v] = w;
    }
}

extern "C" void kernel_launch(void* const* d_in, const int* in_sizes, int n_in,
                              void* d_out, int out_size, void* d_ws, size_t ws_size,
                              hipStream_t stream) {
    const float* x  = (const float*)d_in[0];
    const float* Wk = (const float*)d_in[1];
    const float* Wv = (const float*)d_in[2];
    float* out = (float*)d_out;

    char* ws = (char*)d_ws;
    bf16*  Wb    = (bf16*)ws;                           // 256 KB
    bf16*  Kbuf  = (bf16*)(ws + (1 << 20));             // 2 MB
    bf16*  Vt    = (bf16*)(ws + (3 << 20));             // 2 MB
    bf16*  Opart = (bf16*)(ws + (5 << 20));             // 1024*4096*2 = 8 MB
    float* lpart = (float*)(ws + (13 << 20));           // 256 KB

    wconv_kernel<<<128, 256, 0, stream>>>(Wk, Wv, Wb);
    proj_kernel<<<512, 256, 0, stream>>>(x, Wb, Kbuf, Vt);
    attn_kernel<<<1024, 256, 0, stream>>>(Kbuf, Vt, Opart, lpart);
    attn_combine<<<256, 256, 0, stream>>>(Opart, lpart, out);
}